// Round 1
// baseline (164.585 us; speedup 1.0000x reference)
//
#include <hip/hip_runtime.h>
#include <math.h>

#define NN 30000
#define BB 16
#define DD 32
#define KK 8
#define HH 8
#define DIST_C 5.0f
#define EPS_C 1e-6f
#define SCALE_C 0.17677669529663687f  // 1/sqrt(32)

// workspace layout (float offsets)
#define WS_ZMIN 0      // 16 x uint (encoded float)
#define WS_ZMAX 16     // 16 x uint
#define WS_ZSUM 32     // 32 f  [b*2+s]
#define WS_QW   64     // 32 f
#define WS_PK   96     // 256 f [h*32+d]
#define WS_WC   352    // 1024 f [d*32+e]
#define WS_T    1376   // 8192 f [b*512 + (s*8+h)*32 + d]
#define WS_AKG  9568   // 8192 f [b*512 + s*256 + h*32 + e]
#define WS_AVG  17760  // 8192 f
// total 25952 floats = ~104 KB

__device__ __forceinline__ unsigned fencode(float f) {
    unsigned u = __float_as_uint(f);
    return (u & 0x80000000u) ? ~u : (u | 0x80000000u);
}
__device__ __forceinline__ float fdecode(unsigned c) {
    return __uint_as_float((c & 0x80000000u) ? (c ^ 0x80000000u) : ~c);
}
__device__ __forceinline__ float silu(float x) { return x / (1.0f + expf(-x)); }

// ---------------------------------------------------------------- init
__global__ __launch_bounds__(256) void k_init(const float* __restrict__ init_dummy,
                                              const float* __restrict__ Wq_dummy,
                                              const float* __restrict__ Wdot,
                                              const float* __restrict__ W2_kd,
                                              const float* __restrict__ Wq_graph,
                                              float* __restrict__ ws) {
    __shared__ float qvec[32];
    __shared__ float qWl[32];
    int t = threadIdx.x;
    unsigned* wsu = (unsigned*)ws;
    if (t < 16) { wsu[WS_ZMIN + t] = 0xFFFFFFFFu; wsu[WS_ZMAX + t] = 0u; }
    if (t < 32) ws[WS_ZSUM + t] = 0.0f;
    for (int i = t; i < 8192; i += 256) ws[WS_T + i] = 0.0f;
    if (t < 32) {
        float acc = 0.0f;
        for (int d = 0; d < 32; ++d) acc += init_dummy[d] * Wq_dummy[d * 32 + t];
        qvec[t] = acc;
    }
    __syncthreads();
    if (t < 32) {
        float acc = 0.0f;
        for (int e = 0; e < 32; ++e) acc += qvec[e] * Wdot[e * 32 + t];
        qWl[t] = acc;
        ws[WS_QW + t] = acc;
    }
    __syncthreads();
    {   // P_k[h][d] = sum_e W2_kd[h,d*32+e] * qW[e]
        int h = t >> 5, d = t & 31;
        float acc = 0.0f;
        for (int e = 0; e < 32; ++e) acc += W2_kd[h * 1024 + d * 32 + e] * qWl[e];
        ws[WS_PK + t] = acc;
    }
    for (int i = t; i < 1024; i += 256) {  // Wcomb = Wq_graph @ Wdot
        int d = i >> 5, e = i & 31;
        float acc = 0.0f;
        for (int m = 0; m < 32; ++m) acc += Wq_graph[d * 32 + m] * Wdot[m * 32 + e];
        ws[WS_WC + i] = acc;
    }
}

// ---------------------------------------------------------------- z min/max per batch
__global__ __launch_bounds__(256) void k_zminmax(const float* __restrict__ pos,
                                                 const int* __restrict__ batch,
                                                 float* __restrict__ ws) {
    __shared__ unsigned zl[16], zh[16];
    int t = threadIdx.x;
    if (t < 16) { zl[t] = 0xFFFFFFFFu; zh[t] = 0u; }
    __syncthreads();
    int n = blockIdx.x * 256 + t;
    if (n < NN) {
        unsigned c = fencode(pos[3 * n + 2]);
        int b = batch[n];
        atomicMin(&zl[b], c);
        atomicMax(&zh[b], c);
    }
    __syncthreads();
    unsigned* wsu = (unsigned*)ws;
    if (t < 16) {
        if (zl[t] != 0xFFFFFFFFu) atomicMin(&wsu[WS_ZMIN + t], zl[t]);
        if (zh[t] != 0u)          atomicMax(&wsu[WS_ZMAX + t], zh[t]);
    }
}

// ---------------------------------------------------------------- phase 1: s, e, zsum, T
__global__ __launch_bounds__(256) void k_phase1(const float* __restrict__ pos,
                                                const int* __restrict__ batch,
                                                const float* __restrict__ nf,
                                                const float* __restrict__ bw,
                                                const float* __restrict__ W1_kd,
                                                const float* __restrict__ W1_vd,
                                                float* __restrict__ ws) {
    __shared__ float Lw[256 * 16];
    __shared__ float Lf[256 * 32];
    __shared__ int   Lb[256];
    __shared__ float W1kd[64], W1vd[64], Pk[256], zsl[32], bwl[8];
    int t = threadIdx.x;
    if (t < 64) { W1kd[t] = W1_kd[t]; W1vd[t] = W1_vd[t]; }
    Pk[t] = ws[WS_PK + t];
    if (t < 32) zsl[t] = 0.0f;
    if (t < 8) bwl[t] = bw[t];
    __syncthreads();

    int n = blockIdx.x * 256 + t;
    if (n < NN) {
        int b = batch[n];
        unsigned* wsu = (unsigned*)ws;
        float z = pos[3 * n + 2];
        float zmin = fdecode(wsu[WS_ZMIN + b]);
        float zmax = fdecode(wsu[WS_ZMAX + b]);
        float xl[2];
        xl[0] = z - zmin + DIST_C;
        xl[1] = zmax + DIST_C - z;
        float edge[2][8];
        #pragma unroll
        for (int s = 0; s < 2; ++s) {
            float inv = 1.0f / (xl[s] + EPS_C);
            #pragma unroll
            for (int k = 0; k < 8; ++k) edge[s][k] = sinf(bwl[k] * xl[s]) * inv;
        }
        // node features -> regs + LDS
        float f[32];
        const float4* nf4 = (const float4*)nf;
        float4* Lf4 = (float4*)Lf;
        #pragma unroll
        for (int j = 0; j < 8; ++j) {
            float4 v = nf4[n * 8 + j];
            f[4 * j] = v.x; f[4 * j + 1] = v.y; f[4 * j + 2] = v.z; f[4 * j + 3] = v.w;
            Lf4[t * 8 + j] = v;
        }
        // u[h] = f . P_k[h,:]
        float u[8];
        #pragma unroll
        for (int h = 0; h < 8; ++h) {
            float acc = 0.0f;
            #pragma unroll
            for (int d = 0; d < 32; ++d) acc += f[d] * Pk[h * 32 + d];
            u[h] = acc;
        }
        // s, e per side; then vd activations -> Lw
        float ev[2];
        #pragma unroll
        for (int s = 0; s < 2; ++s) {
            float sacc = 0.0f;
            #pragma unroll
            for (int h = 0; h < 8; ++h) {
                float pre = 0.0f;
                #pragma unroll
                for (int k = 0; k < 8; ++k) pre += edge[s][k] * W1kd[k * 8 + h];
                sacc += silu(pre) * u[h];
            }
            ev[s] = expf(sacc * SCALE_C);
            atomicAdd(&zsl[b * 2 + s], ev[s]);
        }
        #pragma unroll
        for (int s = 0; s < 2; ++s) {
            #pragma unroll
            for (int h = 0; h < 8; ++h) {
                float pre = 0.0f;
                #pragma unroll
                for (int k = 0; k < 8; ++k) pre += edge[s][k] * W1vd[k * 8 + h];
                Lw[t * 16 + s * 8 + h] = ev[s] * silu(pre);
            }
        }
        Lb[t] = b;
    } else {
        Lb[t] = -1;
    }
    __syncthreads();
    if (t < 32 && zsl[t] != 0.0f) atomicAdd(&ws[WS_ZSUM + t], zsl[t]);

    int base = blockIdx.x * 256;
    int count = NN - base; if (count > 256) count = 256;
    int bf = Lb[0], bl = Lb[count - 1];
    int sh = t >> 4;
    int d0 = (t & 15) * 2;
    const float2* Lf2 = (const float2*)Lf;
    for (int b2 = bf; b2 <= bl; ++b2) {
        float a0 = 0.0f, a1 = 0.0f;
        for (int i = 0; i < count; ++i) {
            if (Lb[i] == b2) {
                float w = Lw[i * 16 + sh];
                float2 fv = Lf2[i * 16 + (d0 >> 1)];
                a0 += w * fv.x;
                a1 += w * fv.y;
            }
        }
        atomicAdd(&ws[WS_T + b2 * 512 + sh * 32 + d0],     a0);
        atomicAdd(&ws[WS_T + b2 * 512 + sh * 32 + d0 + 1], a1);
    }
}

// ---------------------------------------------------------------- per-(b,s): dummy_new, A_kg, A_vg
__global__ __launch_bounds__(256) void k_batch(const float* __restrict__ init_dummy,
                                               const float* __restrict__ W2_vd,
                                               const float* __restrict__ W2_kg,
                                               const float* __restrict__ W2_vg,
                                               float* __restrict__ ws) {
    int bs = blockIdx.x;
    int b = bs >> 1, s = bs & 1;
    int t = threadIdx.x;
    __shared__ float Tl[256];
    __shared__ float dn[32];
    Tl[t] = ws[WS_T + b * 512 + s * 256 + t];
    __syncthreads();
    if (t < 32) {
        float acc = 0.0f;
        #pragma unroll
        for (int h = 0; h < 8; ++h) {
            #pragma unroll
            for (int d = 0; d < 32; ++d)
                acc += Tl[h * 32 + d] * W2_vd[h * 1024 + d * 32 + t];
        }
        float zs = ws[WS_ZSUM + b * 2 + s];
        dn[t] = init_dummy[t] + acc / zs;
    }
    __syncthreads();
    {
        int h = t >> 5, e = t & 31;
        float ak = 0.0f, av = 0.0f;
        #pragma unroll
        for (int d = 0; d < 32; ++d) {
            float dv = dn[d];
            ak += dv * W2_kg[h * 1024 + d * 32 + e];
            av += dv * W2_vg[h * 1024 + d * 32 + e];
        }
        ws[WS_AKG + b * 512 + s * 256 + t] = ak;
        ws[WS_AVG + b * 512 + s * 256 + t] = av;
    }
}

// ---------------------------------------------------------------- finale: per-node output
__global__ __launch_bounds__(256) void k_final(const float* __restrict__ pos,
                                               const int* __restrict__ batch,
                                               const float* __restrict__ nf,
                                               const float* __restrict__ bw,
                                               const float* __restrict__ W1_kg,
                                               const float* __restrict__ W1_vg,
                                               const float* __restrict__ ws,
                                               float* __restrict__ out) {
    __shared__ float Wc[1024];
    __shared__ float W1kg[64], W1vg[64], bwl[8];
    int t = threadIdx.x;
    for (int i = t; i < 1024; i += 256) Wc[i] = ws[WS_WC + i];
    if (t < 64) { W1kg[t] = W1_kg[t]; W1vg[t] = W1_vg[t]; }
    if (t < 8) bwl[t] = bw[t];
    __syncthreads();
    int n = blockIdx.x * 256 + t;
    if (n >= NN) return;

    int b = batch[n];
    const unsigned* wsu = (const unsigned*)ws;
    float z = pos[3 * n + 2];
    float zmin = fdecode(wsu[WS_ZMIN + b]);
    float zmax = fdecode(wsu[WS_ZMAX + b]);
    float xl[2];
    xl[0] = z - zmin + DIST_C;
    xl[1] = zmax + DIST_C - z;
    float edge[2][8];
    #pragma unroll
    for (int s = 0; s < 2; ++s) {
        float inv = 1.0f / (xl[s] + EPS_C);
        #pragma unroll
        for (int k = 0; k < 8; ++k) edge[s][k] = sinf(bwl[k] * xl[s]) * inv;
    }
    float akg[2][8], avgg[2][8];
    #pragma unroll
    for (int s = 0; s < 2; ++s) {
        #pragma unroll
        for (int h = 0; h < 8; ++h) {
            float pk = 0.0f, pv = 0.0f;
            #pragma unroll
            for (int k = 0; k < 8; ++k) {
                pk += edge[s][k] * W1kg[k * 8 + h];
                pv += edge[s][k] * W1vg[k * 8 + h];
            }
            akg[s][h] = silu(pk);
            avgg[s][h] = silu(pv);
        }
    }
    // load f
    float f[32];
    const float4* nf4 = (const float4*)nf;
    float4 fv4[8];
    #pragma unroll
    for (int j = 0; j < 8; ++j) {
        float4 v = nf4[n * 8 + j];
        fv4[j] = v;
        f[4 * j] = v.x; f[4 * j + 1] = v.y; f[4 * j + 2] = v.z; f[4 * j + 3] = v.w;
    }
    // qgW = f @ Wcomb
    float4 q4[8];
    #pragma unroll
    for (int j = 0; j < 8; ++j) { q4[j].x = 0; q4[j].y = 0; q4[j].z = 0; q4[j].w = 0; }
    const float4* Wc4 = (const float4*)Wc;
    #pragma unroll
    for (int d = 0; d < 32; ++d) {
        float fd = f[d];
        #pragma unroll
        for (int j = 0; j < 8; ++j) {
            float4 w = Wc4[d * 8 + j];
            q4[j].x += fd * w.x; q4[j].y += fd * w.y; q4[j].z += fd * w.z; q4[j].w += fd * w.w;
        }
    }
    // sg[s] = scale * sum_h akg[s][h] * (qgW . A_kg[b,s,h,:])
    const float4* Ak4 = (const float4*)(ws + WS_AKG);
    const float4* Av4 = (const float4*)(ws + WS_AVG);
    float sg[2];
    #pragma unroll
    for (int s = 0; s < 2; ++s) {
        float acc = 0.0f;
        #pragma unroll
        for (int h = 0; h < 8; ++h) {
            int rb = b * 128 + s * 64 + h * 8;
            float dotv = 0.0f;
            #pragma unroll
            for (int j = 0; j < 8; ++j) {
                float4 a = Ak4[rb + j];
                dotv += q4[j].x * a.x + q4[j].y * a.y + q4[j].z * a.z + q4[j].w * a.w;
            }
            acc += akg[s][h] * dotv;
        }
        sg[s] = acc * SCALE_C;
    }
    float mm = fmaxf(sg[0], sg[1]);
    float e0 = expf(sg[0] - mm), e1 = expf(sg[1] - mm);
    float inv = 1.0f / (e0 + e1);
    float ag0 = e0 * inv, ag1 = e1 * inv;
    // x = f + sum_{s,h} ag[s]*avgg[s][h] * A_vg[b,s,h,:]
    float4 x4[8];
    #pragma unroll
    for (int j = 0; j < 8; ++j) x4[j] = fv4[j];
    #pragma unroll
    for (int s = 0; s < 2; ++s) {
        float ags = (s == 0) ? ag0 : ag1;
        #pragma unroll
        for (int h = 0; h < 8; ++h) {
            float wv = ags * avgg[s][h];
            int rb = b * 128 + s * 64 + h * 8;
            #pragma unroll
            for (int j = 0; j < 8; ++j) {
                float4 a = Av4[rb + j];
                x4[j].x += wv * a.x; x4[j].y += wv * a.y; x4[j].z += wv * a.z; x4[j].w += wv * a.w;
            }
        }
    }
    float4* out4 = (float4*)out;
    #pragma unroll
    for (int j = 0; j < 8; ++j) out4[n * 8 + j] = x4[j];
}

extern "C" void kernel_launch(void* const* d_in, const int* in_sizes, int n_in,
                              void* d_out, int out_size, void* d_ws, size_t ws_size,
                              hipStream_t stream) {
    const float* pos        = (const float*)d_in[0];
    const float* nf         = (const float*)d_in[1];
    const int*   batch      = (const int*)d_in[2];
    const float* bw         = (const float*)d_in[3];
    const float* init_dummy = (const float*)d_in[4];
    const float* Wq_dummy   = (const float*)d_in[5];
    const float* Wq_graph   = (const float*)d_in[6];
    const float* Wdot       = (const float*)d_in[7];
    const float* W1_kd      = (const float*)d_in[8];
    const float* W2_kd      = (const float*)d_in[9];
    const float* W1_vd      = (const float*)d_in[10];
    const float* W2_vd      = (const float*)d_in[11];
    const float* W1_kg      = (const float*)d_in[12];
    const float* W2_kg      = (const float*)d_in[13];
    const float* W1_vg      = (const float*)d_in[14];
    const float* W2_vg      = (const float*)d_in[15];
    float* ws  = (float*)d_ws;
    float* out = (float*)d_out;

    int nblk = (NN + 255) / 256;
    hipLaunchKernelGGL(k_init, dim3(1), dim3(256), 0, stream,
                       init_dummy, Wq_dummy, Wdot, W2_kd, Wq_graph, ws);
    hipLaunchKernelGGL(k_zminmax, dim3(nblk), dim3(256), 0, stream, pos, batch, ws);
    hipLaunchKernelGGL(k_phase1, dim3(nblk), dim3(256), 0, stream,
                       pos, batch, nf, bw, W1_kd, W1_vd, ws);
    hipLaunchKernelGGL(k_batch, dim3(32), dim3(256), 0, stream,
                       init_dummy, W2_vd, W2_kg, W2_vg, ws);
    hipLaunchKernelGGL(k_final, dim3(nblk), dim3(256), 0, stream,
                       pos, batch, nf, bw, W1_kg, W1_vg, ws, out);
}

// Round 2
// 147.016 us; speedup vs baseline: 1.1195x; 1.1195x over previous
//
#include <hip/hip_runtime.h>
#include <math.h>

#define NN 30000
#define BB 16
#define DD 32
#define KK 8
#define HH 8
#define DIST_C 5.0f
#define EPS_C 1e-6f
#define SCALE_C 0.17677669529663687f  // 1/sqrt(32)

// workspace layout (float offsets)
#define WS_ZMIN 0      // 16 x uint (encoded float)
#define WS_ZMAX 16     // 16 x uint
#define WS_ZSUM 32     // 32 f  [b*2+s]
#define WS_QW   64     // 32 f
#define WS_PK   96     // 256 f [h*32+d]
#define WS_WC   352    // 1024 f [d*32+e]
#define WS_T    1376   // 8192 f [b*512 + (s*8+h)*32 + d]
#define WS_AKG  9568   // 8192 f [b*512 + s*256 + h*32 + e]
#define WS_AVG  17760  // 8192 f

__device__ __forceinline__ unsigned fencode(float f) {
    unsigned u = __float_as_uint(f);
    return (u & 0x80000000u) ? ~u : (u | 0x80000000u);
}
__device__ __forceinline__ float fdecode(unsigned c) {
    return __uint_as_float((c & 0x80000000u) ? (c ^ 0x80000000u) : ~c);
}
__device__ __forceinline__ float silu(float x) { return x / (1.0f + expf(-x)); }

// ---------------------------------------------------------------- init
__global__ __launch_bounds__(256) void k_init(const float* __restrict__ init_dummy,
                                              const float* __restrict__ Wq_dummy,
                                              const float* __restrict__ Wdot,
                                              const float* __restrict__ W2_kd,
                                              const float* __restrict__ Wq_graph,
                                              float* __restrict__ ws) {
    __shared__ float qvec[32];
    __shared__ float qWl[32];
    int t = threadIdx.x;
    unsigned* wsu = (unsigned*)ws;
    if (t < 16) { wsu[WS_ZMIN + t] = 0xFFFFFFFFu; wsu[WS_ZMAX + t] = 0u; }
    if (t < 32) ws[WS_ZSUM + t] = 0.0f;
    for (int i = t; i < 8192; i += 256) ws[WS_T + i] = 0.0f;
    if (t < 32) {
        float acc = 0.0f;
        for (int d = 0; d < 32; ++d) acc += init_dummy[d] * Wq_dummy[d * 32 + t];
        qvec[t] = acc;
    }
    __syncthreads();
    if (t < 32) {
        float acc = 0.0f;
        for (int e = 0; e < 32; ++e) acc += qvec[e] * Wdot[e * 32 + t];
        qWl[t] = acc;
        ws[WS_QW + t] = acc;
    }
    __syncthreads();
    {   // P_k[h][d] = sum_e W2_kd[h,d*32+e] * qW[e]
        int h = t >> 5, d = t & 31;
        float acc = 0.0f;
        for (int e = 0; e < 32; ++e) acc += W2_kd[h * 1024 + d * 32 + e] * qWl[e];
        ws[WS_PK + t] = acc;
    }
    for (int i = t; i < 1024; i += 256) {  // Wcomb = Wq_graph @ Wdot
        int d = i >> 5, e = i & 31;
        float acc = 0.0f;
        for (int m = 0; m < 32; ++m) acc += Wq_graph[d * 32 + m] * Wdot[m * 32 + e];
        ws[WS_WC + i] = acc;
    }
}

// ---------------------------------------------------------------- z min/max per batch
__global__ __launch_bounds__(256) void k_zminmax(const float* __restrict__ pos,
                                                 const int* __restrict__ batch,
                                                 float* __restrict__ ws) {
    __shared__ unsigned zl[16], zh[16];
    int t = threadIdx.x;
    if (t < 16) { zl[t] = 0xFFFFFFFFu; zh[t] = 0u; }
    __syncthreads();
    int n = blockIdx.x * 256 + t;
    if (n < NN) {
        unsigned c = fencode(pos[3 * n + 2]);
        int b = batch[n];
        atomicMin(&zl[b], c);
        atomicMax(&zh[b], c);
    }
    __syncthreads();
    unsigned* wsu = (unsigned*)ws;
    if (t < 16) {
        if (zl[t] != 0xFFFFFFFFu) atomicMin(&wsu[WS_ZMIN + t], zl[t]);
        if (zh[t] != 0u)          atomicMax(&wsu[WS_ZMAX + t], zh[t]);
    }
}

// ---------------------------------------------------------------- phase 1: s, e, zsum, T
// LDS strides: Lw row = 17 floats (write bank = (17t+idx)%32, conflict-free);
// Lf row = 36 floats = 144 B (16B-aligned; b128 write start bank = (36t)%32 = 4t%32,
// each 8 consecutive lanes cover all 32 banks -> conflict-free).
#define LWS 17
#define LFS 36
__global__ __launch_bounds__(256) void k_phase1(const float* __restrict__ pos,
                                                const int* __restrict__ batch,
                                                const float* __restrict__ nf,
                                                const float* __restrict__ bw,
                                                const float* __restrict__ W1_kd,
                                                const float* __restrict__ W1_vd,
                                                float* __restrict__ ws) {
    __shared__ float Lw[256 * LWS];
    __shared__ float Lf[256 * LFS];
    __shared__ int   Lb[256];
    __shared__ float W1kd[64], W1vd[64], Pk[256], zsl[32], bwl[8];
    int t = threadIdx.x;
    if (t < 64) { W1kd[t] = W1_kd[t]; W1vd[t] = W1_vd[t]; }
    Pk[t] = ws[WS_PK + t];
    if (t < 32) zsl[t] = 0.0f;
    if (t < 8) bwl[t] = bw[t];
    __syncthreads();

    int n = blockIdx.x * 256 + t;
    if (n < NN) {
        int b = batch[n];
        unsigned* wsu = (unsigned*)ws;
        float z = pos[3 * n + 2];
        float zmin = fdecode(wsu[WS_ZMIN + b]);
        float zmax = fdecode(wsu[WS_ZMAX + b]);
        float xl[2];
        xl[0] = z - zmin + DIST_C;
        xl[1] = zmax + DIST_C - z;
        float edge[2][8];
        #pragma unroll
        for (int s = 0; s < 2; ++s) {
            float inv = 1.0f / (xl[s] + EPS_C);
            #pragma unroll
            for (int k = 0; k < 8; ++k) edge[s][k] = sinf(bwl[k] * xl[s]) * inv;
        }
        // node features -> regs + LDS (padded rows)
        float f[32];
        const float4* nf4 = (const float4*)nf;
        float4* Lf4 = (float4*)Lf;
        #pragma unroll
        for (int j = 0; j < 8; ++j) {
            float4 v = nf4[n * 8 + j];
            f[4 * j] = v.x; f[4 * j + 1] = v.y; f[4 * j + 2] = v.z; f[4 * j + 3] = v.w;
            Lf4[t * 9 + j] = v;   // 9 float4 = 36 floats stride
        }
        // u[h] = f . P_k[h,:]
        float u[8];
        #pragma unroll
        for (int h = 0; h < 8; ++h) {
            float acc = 0.0f;
            #pragma unroll
            for (int d = 0; d < 32; ++d) acc += f[d] * Pk[h * 32 + d];
            u[h] = acc;
        }
        float ev[2];
        #pragma unroll
        for (int s = 0; s < 2; ++s) {
            float sacc = 0.0f;
            #pragma unroll
            for (int h = 0; h < 8; ++h) {
                float pre = 0.0f;
                #pragma unroll
                for (int k = 0; k < 8; ++k) pre += edge[s][k] * W1kd[k * 8 + h];
                sacc += silu(pre) * u[h];
            }
            ev[s] = expf(sacc * SCALE_C);
            atomicAdd(&zsl[b * 2 + s], ev[s]);
        }
        #pragma unroll
        for (int s = 0; s < 2; ++s) {
            #pragma unroll
            for (int h = 0; h < 8; ++h) {
                float pre = 0.0f;
                #pragma unroll
                for (int k = 0; k < 8; ++k) pre += edge[s][k] * W1vd[k * 8 + h];
                Lw[t * LWS + s * 8 + h] = ev[s] * silu(pre);
            }
        }
        Lb[t] = b;
    } else {
        Lb[t] = -1;
    }
    __syncthreads();
    if (t < 32 && zsl[t] != 0.0f) atomicAdd(&ws[WS_ZSUM + t], zsl[t]);

    // ---- segment outer-product reduce: T[b] += W^T(16 x n) @ F(n x 32)
    // wave w reduces node slice [w*64, w*64+64); lane owns (sh = lane&15,
    // d = (lane>>4)*8 + j, j=0..7) -> 8 independent accumulators.
    int base = blockIdx.x * 256;
    int count = NN - base; if (count > 256) count = 256;
    int bf = Lb[0], bl = Lb[count - 1];
    int wave = t >> 6, lane = t & 63;
    int sh = lane & 15;
    int dg = lane >> 4;          // 0..3
    int i0 = wave * 64;
    int i1 = i0 + 64; if (i1 > count) i1 = count;
    const float4* Lf4r = (const float4*)Lf;
    for (int b2 = bf; b2 <= bl; ++b2) {
        float a0 = 0.f, a1 = 0.f, a2 = 0.f, a3 = 0.f;
        float a4 = 0.f, a5 = 0.f, a6 = 0.f, a7 = 0.f;
        for (int i = i0; i < i1; ++i) {
            if (Lb[i] != b2) continue;
            float w = Lw[i * LWS + sh];
            float4 x0 = Lf4r[i * 9 + 2 * dg];
            float4 x1 = Lf4r[i * 9 + 2 * dg + 1];
            a0 += w * x0.x; a1 += w * x0.y; a2 += w * x0.z; a3 += w * x0.w;
            a4 += w * x1.x; a5 += w * x1.y; a6 += w * x1.z; a7 += w * x1.w;
        }
        float* Tb = ws + WS_T + b2 * 512 + sh * 32 + dg * 8;
        atomicAdd(&Tb[0], a0); atomicAdd(&Tb[1], a1);
        atomicAdd(&Tb[2], a2); atomicAdd(&Tb[3], a3);
        atomicAdd(&Tb[4], a4); atomicAdd(&Tb[5], a5);
        atomicAdd(&Tb[6], a6); atomicAdd(&Tb[7], a7);
    }
}

// ---------------------------------------------------------------- per-(b,s): dummy_new, A_kg, A_vg
__global__ __launch_bounds__(256) void k_batch(const float* __restrict__ init_dummy,
                                               const float* __restrict__ W2_vd,
                                               const float* __restrict__ W2_kg,
                                               const float* __restrict__ W2_vg,
                                               float* __restrict__ ws) {
    int bs = blockIdx.x;
    int b = bs >> 1, s = bs & 1;
    int t = threadIdx.x;
    __shared__ float Tl[256];
    __shared__ float dn[32];
    Tl[t] = ws[WS_T + b * 512 + s * 256 + t];
    __syncthreads();
    if (t < 32) {
        float acc = 0.0f;
        #pragma unroll
        for (int h = 0; h < 8; ++h) {
            #pragma unroll
            for (int d = 0; d < 32; ++d)
                acc += Tl[h * 32 + d] * W2_vd[h * 1024 + d * 32 + t];
        }
        float zs = ws[WS_ZSUM + b * 2 + s];
        dn[t] = init_dummy[t] + acc / zs;
    }
    __syncthreads();
    {
        int h = t >> 5, e = t & 31;
        float ak = 0.0f, av = 0.0f;
        #pragma unroll
        for (int d = 0; d < 32; ++d) {
            float dv = dn[d];
            ak += dv * W2_kg[h * 1024 + d * 32 + e];
            av += dv * W2_vg[h * 1024 + d * 32 + e];
        }
        ws[WS_AKG + b * 512 + s * 256 + t] = ak;
        ws[WS_AVG + b * 512 + s * 256 + t] = av;
    }
}

// ---------------------------------------------------------------- finale: per-node output
__global__ __launch_bounds__(256) void k_final(const float* __restrict__ pos,
                                               const int* __restrict__ batch,
                                               const float* __restrict__ nf,
                                               const float* __restrict__ bw,
                                               const float* __restrict__ W1_kg,
                                               const float* __restrict__ W1_vg,
                                               const float* __restrict__ ws,
                                               float* __restrict__ out) {
    __shared__ float Wc[1024];
    __shared__ float W1kg[64], W1vg[64], bwl[8];
    int t = threadIdx.x;
    for (int i = t; i < 1024; i += 256) Wc[i] = ws[WS_WC + i];
    if (t < 64) { W1kg[t] = W1_kg[t]; W1vg[t] = W1_vg[t]; }
    if (t < 8) bwl[t] = bw[t];
    __syncthreads();
    int n = blockIdx.x * 256 + t;
    if (n >= NN) return;

    int b = batch[n];
    const unsigned* wsu = (const unsigned*)ws;
    float z = pos[3 * n + 2];
    float zmin = fdecode(wsu[WS_ZMIN + b]);
    float zmax = fdecode(wsu[WS_ZMAX + b]);
    float xl[2];
    xl[0] = z - zmin + DIST_C;
    xl[1] = zmax + DIST_C - z;
    float edge[2][8];
    #pragma unroll
    for (int s = 0; s < 2; ++s) {
        float inv = 1.0f / (xl[s] + EPS_C);
        #pragma unroll
        for (int k = 0; k < 8; ++k) edge[s][k] = sinf(bwl[k] * xl[s]) * inv;
    }
    float akg[2][8], avgg[2][8];
    #pragma unroll
    for (int s = 0; s < 2; ++s) {
        #pragma unroll
        for (int h = 0; h < 8; ++h) {
            float pk = 0.0f, pv = 0.0f;
            #pragma unroll
            for (int k = 0; k < 8; ++k) {
                pk += edge[s][k] * W1kg[k * 8 + h];
                pv += edge[s][k] * W1vg[k * 8 + h];
            }
            akg[s][h] = silu(pk);
            avgg[s][h] = silu(pv);
        }
    }
    float f[32];
    const float4* nf4 = (const float4*)nf;
    float4 fv4[8];
    #pragma unroll
    for (int j = 0; j < 8; ++j) {
        float4 v = nf4[n * 8 + j];
        fv4[j] = v;
        f[4 * j] = v.x; f[4 * j + 1] = v.y; f[4 * j + 2] = v.z; f[4 * j + 3] = v.w;
    }
    float4 q4[8];
    #pragma unroll
    for (int j = 0; j < 8; ++j) { q4[j].x = 0; q4[j].y = 0; q4[j].z = 0; q4[j].w = 0; }
    const float4* Wc4 = (const float4*)Wc;
    #pragma unroll
    for (int d = 0; d < 32; ++d) {
        float fd = f[d];
        #pragma unroll
        for (int j = 0; j < 8; ++j) {
            float4 w = Wc4[d * 8 + j];
            q4[j].x += fd * w.x; q4[j].y += fd * w.y; q4[j].z += fd * w.z; q4[j].w += fd * w.w;
        }
    }
    const float4* Ak4 = (const float4*)(ws + WS_AKG);
    const float4* Av4 = (const float4*)(ws + WS_AVG);
    float sg[2];
    #pragma unroll
    for (int s = 0; s < 2; ++s) {
        float acc = 0.0f;
        #pragma unroll
        for (int h = 0; h < 8; ++h) {
            int rb = b * 128 + s * 64 + h * 8;
            float dotv = 0.0f;
            #pragma unroll
            for (int j = 0; j < 8; ++j) {
                float4 a = Ak4[rb + j];
                dotv += q4[j].x * a.x + q4[j].y * a.y + q4[j].z * a.z + q4[j].w * a.w;
            }
            acc += akg[s][h] * dotv;
        }
        sg[s] = acc * SCALE_C;
    }
    float mm = fmaxf(sg[0], sg[1]);
    float e0 = expf(sg[0] - mm), e1 = expf(sg[1] - mm);
    float inv = 1.0f / (e0 + e1);
    float ag0 = e0 * inv, ag1 = e1 * inv;
    float4 x4[8];
    #pragma unroll
    for (int j = 0; j < 8; ++j) x4[j] = fv4[j];
    #pragma unroll
    for (int s = 0; s < 2; ++s) {
        float ags = (s == 0) ? ag0 : ag1;
        #pragma unroll
        for (int h = 0; h < 8; ++h) {
            float wv = ags * avgg[s][h];
            int rb = b * 128 + s * 64 + h * 8;
            #pragma unroll
            for (int j = 0; j < 8; ++j) {
                float4 a = Av4[rb + j];
                x4[j].x += wv * a.x; x4[j].y += wv * a.y; x4[j].z += wv * a.z; x4[j].w += wv * a.w;
            }
        }
    }
    float4* out4 = (float4*)out;
    #pragma unroll
    for (int j = 0; j < 8; ++j) out4[n * 8 + j] = x4[j];
}

extern "C" void kernel_launch(void* const* d_in, const int* in_sizes, int n_in,
                              void* d_out, int out_size, void* d_ws, size_t ws_size,
                              hipStream_t stream) {
    const float* pos        = (const float*)d_in[0];
    const float* nf         = (const float*)d_in[1];
    const int*   batch      = (const int*)d_in[2];
    const float* bw         = (const float*)d_in[3];
    const float* init_dummy = (const float*)d_in[4];
    const float* Wq_dummy   = (const float*)d_in[5];
    const float* Wq_graph   = (const float*)d_in[6];
    const float* Wdot       = (const float*)d_in[7];
    const float* W1_kd      = (const float*)d_in[8];
    const float* W2_kd      = (const float*)d_in[9];
    const float* W1_vd      = (const float*)d_in[10];
    const float* W2_vd      = (const float*)d_in[11];
    const float* W1_kg      = (const float*)d_in[12];
    const float* W2_kg      = (const float*)d_in[13];
    const float* W1_vg      = (const float*)d_in[14];
    const float* W2_vg      = (const float*)d_in[15];
    float* ws  = (float*)d_ws;
    float* out = (float*)d_out;

    int nblk = (NN + 255) / 256;
    hipLaunchKernelGGL(k_init, dim3(1), dim3(256), 0, stream,
                       init_dummy, Wq_dummy, Wdot, W2_kd, Wq_graph, ws);
    hipLaunchKernelGGL(k_zminmax, dim3(nblk), dim3(256), 0, stream, pos, batch, ws);
    hipLaunchKernelGGL(k_phase1, dim3(nblk), dim3(256), 0, stream,
                       pos, batch, nf, bw, W1_kd, W1_vd, ws);
    hipLaunchKernelGGL(k_batch, dim3(32), dim3(256), 0, stream,
                       init_dummy, W2_vd, W2_kg, W2_vg, ws);
    hipLaunchKernelGGL(k_final, dim3(nblk), dim3(256), 0, stream,
                       pos, batch, nf, bw, W1_kg, W1_vg, ws, out);
}